// Round 4
// baseline (276.223 us; speedup 1.0000x reference)
//
#include <hip/hip_runtime.h>

// BiLinearLayerV2: B=512, F=64, E=32
//   biLinear[b,f,d] = sum_e feature[b,f,e] * weight[f,e,d]
//   out[b,f,g,e]    = biLinear[b,f,e] * feature[b,g,e] * weightLeft[f,g]
// 268 MB fp32 output -> write-BW bound. One block per (b, group of 8 f's):
// 4096 blocks x 256 threads, 64 KiB of output per block (16 float4/thread).
// Stores are nontemporal (nt): output is never re-read, keep L2 for inputs.

#define BDIM 512
#define FDIM 64
#define EDIM 32
#define FPB  8                      // f rows per block
#define NFG  (FDIM / FPB)           // 8 f-groups per b

typedef float f32x4 __attribute__((ext_vector_type(4)));

__global__ __launch_bounds__(256) void bilinear_v2_kernel(
    const float* __restrict__ feature,    // [B,F,E]
    const float* __restrict__ weight,     // [F,E,E]
    const float* __restrict__ weightLeft, // [F,F]
    float* __restrict__ out)              // [B,F,F,E]
{
    const int blk = blockIdx.x;             // b*NFG + fg
    const int fg  = blk & (NFG - 1);
    const int b   = blk >> 3;               // log2(NFG)=3
    const int f0  = fg * FPB;
    const int t   = threadIdx.x;

    __shared__ float s_feat[FDIM * EDIM];   // feature[b,:,:]   8 KiB
    __shared__ float s_bl[FPB * EDIM];      // biLinear rows    1 KiB
    __shared__ float s_wl[FPB * FDIM];      // weightLeft rows  2 KiB

    const float* fb = feature + (size_t)b * (FDIM * EDIM);

    // --- stage feature[b,:,:] : 512 float4, 2 per thread (coalesced) ---
    #pragma unroll
    for (int i = 0; i < 2; ++i) {
        const int idx = t + i * 256;
        reinterpret_cast<f32x4*>(s_feat)[idx] =
            reinterpret_cast<const f32x4*>(fb)[idx];
    }

    // --- stage weightLeft rows f0..f0+7 : 512 floats, 2 per thread ---
    #pragma unroll
    for (int i = 0; i < 2; ++i) {
        const int idx = t + i * 256;            // fl = idx>>6, g = idx&63
        s_wl[idx] = weightLeft[(f0 + (idx >> 6)) * FDIM + (idx & 63)];
    }

    // --- compute biLinear: thread -> (fl = t>>5, d = t&31), 32-MAC dot ---
    {
        const int fl = t >> 5;
        const int d  = t & 31;
        const int f  = f0 + fl;
        const float* fp = fb + f * EDIM;                          // broadcast reads
        const float* wp = weight + (size_t)f * EDIM * EDIM + d;   // coalesced over d
        float acc = 0.f;
        #pragma unroll
        for (int e = 0; e < EDIM; ++e)
            acc += fp[e] * wp[e * EDIM];
        s_bl[fl * EDIM + d] = acc;
    }
    __syncthreads();

    // --- stream out[b, f0..f0+7, :, :] : 4096 float4, 16 per thread ---
    float* op = out + ((size_t)b * FDIM + f0) * (FDIM * EDIM);

    #pragma unroll
    for (int i = 0; i < 16; ++i) {
        const int idx4 = t + i * 256;        // float4 index in [0,4096)
        const int e4   = idx4 & 7;           // float4 within E row
        const int g    = (idx4 >> 3) & 63;
        const int fl   = idx4 >> 9;

        // per-lane LDS addresses are linear in lane -> conflict-free
        const f32x4 fv  = reinterpret_cast<const f32x4*>(s_feat)[g * 8 + e4];
        const f32x4 blv = reinterpret_cast<const f32x4*>(s_bl)[fl * 8 + e4];
        const float w   = s_wl[fl * 64 + g];

        f32x4 o = blv * fv * w;
        __builtin_nontemporal_store(o, reinterpret_cast<f32x4*>(op) + idx4);
    }
}

extern "C" void kernel_launch(void* const* d_in, const int* in_sizes, int n_in,
                              void* d_out, int out_size, void* d_ws, size_t ws_size,
                              hipStream_t stream) {
    const float* feature    = (const float*)d_in[0];
    const float* weight     = (const float*)d_in[1];
    const float* weightLeft = (const float*)d_in[2];
    float* out = (float*)d_out;

    const int nblocks = BDIM * NFG;   // 4096
    bilinear_v2_kernel<<<nblocks, 256, 0, stream>>>(feature, weight, weightLeft, out);
}

// Round 5
// 262.650 us; speedup vs baseline: 1.0517x; 1.0517x over previous
//
#include <hip/hip_runtime.h>

// BiLinearLayerV2: B=512, F=64, E=32
//   biLinear[b,f,d] = sum_e feature[b,f,e] * weight[f,e,d]
//   out[b,f,g,e]    = biLinear[b,f,e] * feature[b,g,e] * weightLeft[f,g]
// 268 MB fp32 output -> write-BW bound. 4096 blocks x 256 threads,
// 64 KiB of output per block (16 float4/thread).
// XCD-aware swizzle: hw maps blk%8 -> XCD, so put the b-RANGE in blk&7:
// each XCD's read working set = 64 b's of feature (512KB) + weight (256KB)
// -> L2-resident, feature fetched from HBM once instead of per-XCD.

#define BDIM 512
#define FDIM 64
#define EDIM 32
#define FPB  8                      // f rows per block
#define NFG  (FDIM / FPB)           // 8 f-groups per b

typedef float f32x4 __attribute__((ext_vector_type(4)));

__global__ __launch_bounds__(256) void bilinear_v2_kernel(
    const float* __restrict__ feature,    // [B,F,E]
    const float* __restrict__ weight,     // [F,E,E]
    const float* __restrict__ weightLeft, // [F,F]
    float* __restrict__ out)              // [B,F,F,E]
{
    const int blk = blockIdx.x;
    // XCD swizzle (bijective, 4096 = 8 xcd * 64 b * 8 fg):
    //   xcd = blk&7 -> owns b in [xcd*64, xcd*64+64)
    const int xcd = blk & 7;
    const int fg  = (blk >> 3) & (NFG - 1);
    const int b   = xcd * (BDIM / 8) + (blk >> 6);
    const int f0  = fg * FPB;
    const int t   = threadIdx.x;

    __shared__ float s_feat[FDIM * EDIM];   // feature[b,:,:]   8 KiB
    __shared__ float s_bl[FPB * EDIM];      // biLinear rows    1 KiB
    __shared__ float s_wl[FPB * FDIM];      // weightLeft rows  2 KiB

    const float* fb = feature + (size_t)b * (FDIM * EDIM);

    // --- stage feature[b,:,:] : 512 float4, 2 per thread (coalesced) ---
    #pragma unroll
    for (int i = 0; i < 2; ++i) {
        const int idx = t + i * 256;
        reinterpret_cast<f32x4*>(s_feat)[idx] =
            reinterpret_cast<const f32x4*>(fb)[idx];
    }

    // --- stage weightLeft rows f0..f0+7 : 512 floats, 2 per thread ---
    #pragma unroll
    for (int i = 0; i < 2; ++i) {
        const int idx = t + i * 256;            // fl = idx>>6, g = idx&63
        s_wl[idx] = weightLeft[(f0 + (idx >> 6)) * FDIM + (idx & 63)];
    }

    // --- compute biLinear: thread -> (fl = t>>5, d = t&31), 32-MAC dot ---
    {
        const int fl = t >> 5;
        const int d  = t & 31;
        const int f  = f0 + fl;
        const float* fp = fb + f * EDIM;                          // broadcast reads
        const float* wp = weight + (size_t)f * EDIM * EDIM + d;   // coalesced over d
        float acc = 0.f;
        #pragma unroll
        for (int e = 0; e < EDIM; ++e)
            acc += fp[e] * wp[e * EDIM];
        s_bl[fl * EDIM + d] = acc;
    }
    __syncthreads();

    // --- stream out[b, f0..f0+7, :, :] : 4096 float4, 16 per thread ---
    float* op = out + ((size_t)b * FDIM + f0) * (FDIM * EDIM);

    #pragma unroll
    for (int i = 0; i < 16; ++i) {
        const int idx4 = t + i * 256;        // float4 index in [0,4096)
        const int e4   = idx4 & 7;           // float4 within E row
        const int g    = (idx4 >> 3) & 63;
        const int fl   = idx4 >> 9;

        // per-lane LDS addresses are linear in lane -> conflict-free
        const f32x4 fv  = reinterpret_cast<const f32x4*>(s_feat)[g * 8 + e4];
        const f32x4 blv = reinterpret_cast<const f32x4*>(s_bl)[fl * 8 + e4];
        const float w   = s_wl[fl * 64 + g];

        f32x4 o = blv * fv * w;
        reinterpret_cast<f32x4*>(op)[idx4] = o;
    }
}

extern "C" void kernel_launch(void* const* d_in, const int* in_sizes, int n_in,
                              void* d_out, int out_size, void* d_ws, size_t ws_size,
                              hipStream_t stream) {
    const float* feature    = (const float*)d_in[0];
    const float* weight     = (const float*)d_in[1];
    const float* weightLeft = (const float*)d_in[2];
    float* out = (float*)d_out;

    const int nblocks = BDIM * NFG;   // 4096
    bilinear_v2_kernel<<<nblocks, 256, 0, stream>>>(feature, weight, weightLeft, out);
}